// Round 8
// baseline (1574.490 us; speedup 1.0000x reference)
//
#include <hip/hip_runtime.h>
#include <hip/hip_bf16.h>
#include <math.h>

#define E 512
#define H_HEADS 8
#define DH 64
#define NLAYER 6
#define DFF 2048
#define SEQ 2048      // T*V
#define NB 2          // batch
#define M_TOK (NB*SEQ) // 4096 rows

typedef float f32x4_t __attribute__((ext_vector_type(4)));
typedef __bf16 bf16x8_t __attribute__((ext_vector_type(8)));
typedef short s16x8_t __attribute__((ext_vector_type(8)));

// float -> bf16 bits, round-to-nearest-even
__device__ __forceinline__ short f2bf(float f) {
    union { float f; unsigned u; } v; v.f = f;
    unsigned r = v.u + 0x7FFFu + ((v.u >> 16) & 1u);
    return (short)(r >> 16);
}
__device__ __forceinline__ float bf2f(short s) {
    union { unsigned u; float f; } v; v.u = ((unsigned)(unsigned short)s) << 16;
    return v.f;
}

__device__ __forceinline__ bf16x8_t mk_frag(short4 lo, short4 hi) {
    s16x8_t t;
    t[0] = lo.x; t[1] = lo.y; t[2] = lo.z; t[3] = lo.w;
    t[4] = hi.x; t[5] = hi.y; t[6] = hi.z; t[7] = hi.w;
    return __builtin_bit_cast(bf16x8_t, t);
}

__device__ __forceinline__ void gload16(const void* g, void* l) {
    __builtin_amdgcn_global_load_lds(
        (const __attribute__((address_space(1))) void*)g,
        (__attribute__((address_space(3))) void*)l, 16, 0, 0);
}

// ---------------- embedding: x = code_emb[idx] + stage + time_pos + joint_pos ----------------
__global__ __launch_bounds__(256) void embed_kernel(
    const int* __restrict__ idx, const float* __restrict__ ce,
    const float* __restrict__ se, const float* __restrict__ tp,
    const float* __restrict__ jp, float* __restrict__ x)
{
    int i = blockIdx.x * 256 + threadIdx.x;   // float4 index, total 524288
    int e4 = i & 127;                          // E/4 = 128
    int row = i >> 7;                          // 0..4095  = b*2048 + t*32 + v
    int v = row & 31;
    int t = (row >> 5) & 63;
    int code = idx[row];
    const float4* ce4 = (const float4*)ce;
    const float4* se4 = (const float4*)se;
    const float4* tp4 = (const float4*)tp;
    const float4* jp4 = (const float4*)jp;
    float4 a = ce4[code * 128 + e4];
    float4 b = se4[e4];
    float4 c = tp4[t * 128 + e4];
    float4 d = jp4[v * 128 + e4];
    float4 o;
    o.x = a.x + b.x + c.x + d.x;
    o.y = a.y + b.y + c.y + d.y;
    o.z = a.z + b.z + c.z + d.z;
    o.w = a.w + b.w + c.w + d.w;
    ((float4*)x)[i] = o;
}

// ---------------- weight cast: one layer's 4 weight mats fp32 -> bf16 ----------------
__global__ __launch_bounds__(256) void cast4_kernel(
    const float* __restrict__ w0, const float* __restrict__ w1,
    const float* __restrict__ w2, const float* __restrict__ w3,
    short* __restrict__ o)
{
    int i = blockIdx.x * 256 + threadIdx.x;   // chunk of 8
    const float* src; int off;
    if (i < 98304)       { src = w0; off = i; }
    else if (i < 131072) { src = w1; off = i - 98304; }
    else if (i < 262144) { src = w2; off = i - 131072; }
    else                 { src = w3; off = i - 262144; }
    float4 a = ((const float4*)src)[off * 2];
    float4 b = ((const float4*)src)[off * 2 + 1];
    s16x8_t s;
    s[0] = f2bf(a.x); s[1] = f2bf(a.y); s[2] = f2bf(a.z); s[3] = f2bf(a.w);
    s[4] = f2bf(b.x); s[5] = f2bf(b.y); s[6] = f2bf(b.z); s[7] = f2bf(b.w);
    *(s16x8_t*)&o[(size_t)i * 8] = s;
}

// ---------------- LayerNorm: one wave per row of 512, bf16 output ----------------
__global__ __launch_bounds__(256) void ln_kernel(
    const float* __restrict__ x, short* __restrict__ y,
    const float* __restrict__ g, const float* __restrict__ b)
{
    int wave = threadIdx.x >> 6;
    int lane = threadIdx.x & 63;
    int row = blockIdx.x * 4 + wave;
    const float4* xr = (const float4*)(x + (size_t)row * E);
    float4 v0 = xr[lane];
    float4 v1 = xr[lane + 64];
    float s  = v0.x + v0.y + v0.z + v0.w + v1.x + v1.y + v1.z + v1.w;
    float ss = v0.x*v0.x + v0.y*v0.y + v0.z*v0.z + v0.w*v0.w
             + v1.x*v1.x + v1.y*v1.y + v1.z*v1.z + v1.w*v1.w;
    #pragma unroll
    for (int off = 32; off; off >>= 1) {
        s  += __shfl_xor(s, off, 64);
        ss += __shfl_xor(ss, off, 64);
    }
    float mu = s * (1.f / E);
    float var = ss * (1.f / E) - mu * mu;
    float rs = rsqrtf(var + 1e-5f);
    const float4* g4 = (const float4*)g;
    const float4* b4 = (const float4*)b;
    float4 gg = g4[lane], bb = b4[lane];
    short4 o;
    o.x = f2bf((v0.x - mu) * rs * gg.x + bb.x);
    o.y = f2bf((v0.y - mu) * rs * gg.y + bb.y);
    o.z = f2bf((v0.z - mu) * rs * gg.z + bb.z);
    o.w = f2bf((v0.w - mu) * rs * gg.w + bb.w);
    *(short4*)&y[(size_t)row * E + lane * 4] = o;
    gg = g4[lane + 64]; bb = b4[lane + 64];
    o.x = f2bf((v1.x - mu) * rs * gg.x + bb.x);
    o.y = f2bf((v1.y - mu) * rs * gg.y + bb.y);
    o.z = f2bf((v1.z - mu) * rs * gg.z + bb.z);
    o.w = f2bf((v1.w - mu) * rs * gg.w + bb.w);
    *(short4*)&y[(size_t)row * E + 256 + lane * 4] = o;
}

// ---------------- bf16 MFMA GEMM (m97 structure) ----------------
// MODE 0: bias -> bf16 out          MODE 1: bias + res -> fp32 out
// MODE 2: gelu(bias+.) -> bf16 out  MODE 3: QKV split: Q,K -> out[4096][1024], V -> vt^T
template<int MODE>
__global__ __launch_bounds__(256) void gemm_mfma_kernel(
    const short* __restrict__ A, const short* __restrict__ W,
    const float* __restrict__ bias, const float* __restrict__ res,
    void* __restrict__ out, short* __restrict__ vt_out, int N, int K)
{
    __shared__ short As[128 * 64];
    __shared__ short Bs[128 * 64];
    int nb = N >> 7;
    int bx = blockIdx.x % nb;
    int by = blockIdx.x / nb;
    int tid = threadIdx.x;
    int lane = tid & 63, g = lane >> 4, l16 = lane & 15;
    int w = tid >> 6, wm = w >> 1, wn = w & 1;
    int wbase = tid & 192;

    f32x4_t acc[4][4] = {};
    const short* Ab = A + (size_t)(by * 128) * K;
    const short* Wb = W + (size_t)(bx * 128) * K;

    for (int k0 = 0; k0 < K; k0 += 64) {
        __syncthreads();
        #pragma unroll
        for (int u = 0; u < 4; ++u) {
            int c = u * 256 + tid;
            int row = c >> 3, c8 = c & 7;
            gload16(Ab + (size_t)row * K + k0 + c8 * 8, As + (u * 256 + wbase) * 8);
            gload16(Wb + (size_t)row * K + k0 + c8 * 8, Bs + (u * 256 + wbase) * 8);
        }
        __syncthreads();
        #pragma unroll
        for (int ks = 0; ks < 2; ++ks) {
            bf16x8_t af[4], bf[4];
            #pragma unroll
            for (int i = 0; i < 4; ++i) {
                af[i] = *(const bf16x8_t*)&As[(wm * 64 + i * 16 + l16) * 64 + ks * 32 + g * 8];
                bf[i] = *(const bf16x8_t*)&Bs[(wn * 64 + i * 16 + l16) * 64 + ks * 32 + g * 8];
            }
            #pragma unroll
            for (int mi = 0; mi < 4; ++mi)
                #pragma unroll
                for (int ni = 0; ni < 4; ++ni)
                    acc[mi][ni] = __builtin_amdgcn_mfma_f32_16x16x32_bf16(
                        af[mi], bf[ni], acc[mi][ni], 0, 0, 0);
        }
    }

    int gm0 = by * 128 + wm * 64;
    int gn0 = bx * 128 + wn * 64;
    #pragma unroll
    for (int ni = 0; ni < 4; ++ni) {
        int gn = gn0 + ni * 16 + l16;
        float bv = bias[gn];
        #pragma unroll
        for (int mi = 0; mi < 4; ++mi) {
            float vals[4];
            #pragma unroll
            for (int r = 0; r < 4; ++r) {
                float v = acc[mi][ni][r] + bv;
                if (MODE == 2) v = 0.5f * v * (1.f + erff(v * 0.70710678118f));
                vals[r] = v;
            }
            int gmB = gm0 + mi * 16 + g * 4;
            if (MODE == 3) {
                if (gn < 1024) {            // Q,K -> [4096][1024] bf16 (uniform per 16-col group)
                    #pragma unroll
                    for (int r = 0; r < 4; ++r)
                        ((short*)out)[(size_t)(gmB + r) * 1024 + gn] = f2bf(vals[r]);
                } else {                    // V -> V^T[(b*512 + hd)][seq], 8B packed
                    short4 pk = { f2bf(vals[0]), f2bf(vals[1]), f2bf(vals[2]), f2bf(vals[3]) };
                    int bb = gmB >> 11, ss = gmB & 2047;
                    *(short4*)&vt_out[((size_t)(bb * 512 + (gn - 1024))) * 2048 + ss] = pk;
                }
            } else if (MODE == 1) {
                #pragma unroll
                for (int r = 0; r < 4; ++r) {
                    float v = vals[r] + res[(size_t)(gmB + r) * N + gn];
                    ((float*)out)[(size_t)(gmB + r) * N + gn] = v;
                }
            } else {
                #pragma unroll
                for (int r = 0; r < 4; ++r)
                    ((short*)out)[(size_t)(gmB + r) * N + gn] = f2bf(vals[r]);
            }
        }
    }
}

// ---------------- MFMA bf16 flash attention, split-K, NO-LDS loop ----------------
// 1 wave per block (64 thr). Wave owns 32 q-rows (one frame) x one 512-key chunk.
// Grid = 4 chunks x 64 qb x 16 bh = 4096 blocks (longest-first; invalid exit).
// All MFMA fragments are direct 8B global loads (K/V L2-resident):
//   K A-frag:  row key = kt+mt*16+l16, k(dh) = 4g+(j&3)+16(j>>2)+32ks
//   Q B-frag:  col q   = qb*32+qi*16+l16, same k(dh) pattern
//   V^T A-frag: row dh = dt*16+l16, k(key) = 4g+(j&3)+16(j>>2)  (from pre-transposed vt)
// Maps identical to the round-2-verified kernel; only the data source changed.
__global__ __launch_bounds__(64) void attn_mfma_kernel(
    const short* __restrict__ qk, const short* __restrict__ vt,
    short* __restrict__ opart, float* __restrict__ mlbuf)
{
    __shared__ __align__(16) float Ol[32 * 68];   // epilogue O^T -> O bounce

    int bid = blockIdx.x;
    int c   = bid & 3;
    int qb  = 63 - ((bid >> 2) & 63);      // longest-first
    int bh  = bid >> 8;                    // 0..15 = b*8+h
    if (c * 16 > qb) return;               // chunk beyond causal bound
    int h = bh & 7, b = bh >> 3;
    int a_ = qb >> 4, r_ = qb & 15;
    int cidx = bh * 160 + (a_ + 1) * (8 * a_ + r_) + c;

    int lane = threadIdx.x & 63;
    int g = lane >> 4, l16 = lane & 15;

    const short* qkb = qk + (size_t)(b * SEQ) * 1024;
    const short* vb  = vt + (size_t)(bh * 64) * 2048;   // [dh][2048]

    // ---- Q^T B-fragments (8 x 8B global loads, once) ----
    bf16x8_t qf[2][2];
    #pragma unroll
    for (int qi = 0; qi < 2; ++qi)
        #pragma unroll
        for (int ks = 0; ks < 2; ++ks) {
            const short* qrow = qkb + (size_t)(qb * 32 + qi * 16 + l16) * 1024 + h * 64;
            short4 lo = *(const short4*)(qrow + 4 * g + 32 * ks);
            short4 hi = *(const short4*)(qrow + 4 * g + 16 + 32 * ks);
            qf[qi][ks] = mk_frag(lo, hi);
        }

    f32x4_t oa[2][4] = {};
    float mrun[2] = {-1e30f, -1e30f}, lrun[2] = {0.f, 0.f};

    int kstart = c * 512;
    int kcend  = min((qb + 1) * 32, kstart + 512);

    for (int kt = kstart; kt < kcend; kt += 32) {
        // ---- K A-frags + V^T A-frags: 16 x 8B global loads (no LDS, no barriers) ----
        bf16x8_t kf[2][2], vf[4];
        #pragma unroll
        for (int mt = 0; mt < 2; ++mt)
            #pragma unroll
            for (int ks = 0; ks < 2; ++ks) {
                const short* krow = qkb + (size_t)(kt + mt * 16 + l16) * 1024 + 512 + h * 64;
                short4 lo = *(const short4*)(krow + 4 * g + 32 * ks);
                short4 hi = *(const short4*)(krow + 4 * g + 16 + 32 * ks);
                kf[mt][ks] = mk_frag(lo, hi);
            }
        #pragma unroll
        for (int dt = 0; dt < 4; ++dt) {
            const short* vrow = vb + (size_t)(dt * 16 + l16) * 2048 + kt;
            short4 lo = *(const short4*)(vrow + 4 * g);
            short4 hi = *(const short4*)(vrow + 16 + 4 * g);
            vf[dt] = mk_frag(lo, hi);
        }

        #pragma unroll
        for (int qi = 0; qi < 2; ++qi) {
            // ---- S^T[key][q] = K @ Q^T ----
            f32x4_t st[2];
            #pragma unroll
            for (int mt = 0; mt < 2; ++mt) {
                f32x4_t acc = {0.f, 0.f, 0.f, 0.f};
                #pragma unroll
                for (int ks = 0; ks < 2; ++ks)
                    acc = __builtin_amdgcn_mfma_f32_16x16x32_bf16(kf[mt][ks], qf[qi][ks], acc, 0, 0, 0);
                st[mt] = acc;
            }
            // ---- online softmax: lane owns q = qi*16+l16; keys 16*mt + 4g + r ----
            float s8[8];
            #pragma unroll
            for (int mt = 0; mt < 2; ++mt)
                #pragma unroll
                for (int r = 0; r < 4; ++r)
                    s8[mt * 4 + r] = st[mt][r] * 0.125f;
            float tm = s8[0];
            #pragma unroll
            for (int j = 1; j < 8; ++j) tm = fmaxf(tm, s8[j]);
            tm = fmaxf(tm, __shfl_xor(tm, 16));
            tm = fmaxf(tm, __shfl_xor(tm, 32));
            float mnew = fmaxf(mrun[qi], tm);
            float cf = __expf(mrun[qi] - mnew);
            mrun[qi] = mnew;
            float ps = 0.f;
            short pb[8];
            #pragma unroll
            for (int j = 0; j < 8; ++j) {
                float p = __expf(s8[j] - mnew);
                ps += p;
                pb[j] = f2bf(p);
            }
            ps += __shfl_xor(ps, 16);
            ps += __shfl_xor(ps, 32);
            lrun[qi] = lrun[qi] * cf + ps;
            #pragma unroll
            for (int dt = 0; dt < 4; ++dt)
                #pragma unroll
                for (int r = 0; r < 4; ++r)
                    oa[qi][dt][r] *= cf;
            s16x8_t pt;
            #pragma unroll
            for (int j = 0; j < 8; ++j) pt[j] = pb[j];
            bf16x8_t pf = __builtin_bit_cast(bf16x8_t, pt);
            // ---- O^T += V^T @ P^T ----
            #pragma unroll
            for (int dt = 0; dt < 4; ++dt)
                oa[qi][dt] = __builtin_amdgcn_mfma_f32_16x16x32_bf16(vf[dt], pf, oa[qi][dt], 0, 0, 0);
        }
    }

    // ---- epilogue: unnormalized O^T -> [q][dh] via LDS bounce (1 wave, no barrier) ----
    #pragma unroll
    for (int qi = 0; qi < 2; ++qi) {
        #pragma unroll
        for (int dt = 0; dt < 4; ++dt)
            #pragma unroll
            for (int r = 0; r < 4; ++r)
                Ol[(qi * 16 + l16) * 68 + 16 * dt + 4 * g + r] = oa[qi][dt][r];
        if (g == 0) {
            mlbuf[cidx * 64 + qi * 16 + l16] = mrun[qi];
            mlbuf[cidx * 64 + 32 + qi * 16 + l16] = lrun[qi];
        }
    }
    int q = lane >> 1, d0 = (lane & 1) * 32;
    const float* orow = &Ol[q * 68 + d0];
    size_t ob = (size_t)cidx * 2048 + q * 64 + d0;
    #pragma unroll
    for (int u = 0; u < 4; ++u) {
        s16x8_t sv;
        #pragma unroll
        for (int j = 0; j < 8; ++j) sv[j] = f2bf(orow[u * 8 + j]);
        *(s16x8_t*)&opart[ob + u * 8] = sv;
    }
}

// ---------------- split-K combine: exp-weighted merge of partials -> y bf16 ----------------
__global__ __launch_bounds__(128) void attn_combine_kernel(
    const short* __restrict__ opart, const float* __restrict__ mlbuf,
    short* __restrict__ y)
{
    int bid = blockIdx.x;
    int qb = bid & 63, bh = bid >> 6;
    int h = bh & 7, b = bh >> 3;
    int a_ = qb >> 4, r_ = qb & 15;
    int cbase = bh * 160 + (a_ + 1) * (8 * a_ + r_);
    int nc = a_ + 1;
    int t = threadIdx.x;
    int q = t >> 2, d0 = (t & 3) * 16;

    float M = -1e30f;
    #pragma unroll
    for (int cc = 0; cc < 4; ++cc)
        if (cc < nc) M = fmaxf(M, mlbuf[(cbase + cc) * 64 + q]);
    float L = 0.f;
    float acc[16] = {};
    #pragma unroll
    for (int cc = 0; cc < 4; ++cc) {
        if (cc < nc) {
            float mv = mlbuf[(cbase + cc) * 64 + q];
            float lv = mlbuf[(cbase + cc) * 64 + 32 + q];
            float wgt = __expf(mv - M);
            L += wgt * lv;
            const short* op = &opart[(size_t)(cbase + cc) * 2048 + q * 64 + d0];
            s16x8_t v0 = *(const s16x8_t*)op;
            s16x8_t v1 = *(const s16x8_t*)(op + 8);
            #pragma unroll
            for (int j = 0; j < 8; ++j) {
                acc[j]     += wgt * bf2f(v0[j]);
                acc[8 + j] += wgt * bf2f(v1[j]);
            }
        }
    }
    float inv = 1.f / L;
    s16x8_t o0, o1;
    #pragma unroll
    for (int j = 0; j < 8; ++j) { o0[j] = f2bf(acc[j] * inv); o1[j] = f2bf(acc[8 + j] * inv); }
    size_t gb = (size_t)(b * SEQ + qb * 32 + q) * E + h * 64 + d0;
    *(s16x8_t*)&y[gb] = o0;
    *(s16x8_t*)&y[gb + 8] = o1;
}

extern "C" void kernel_launch(void* const* d_in, const int* in_sizes, int n_in,
                              void* d_out, int out_size, void* d_ws, size_t ws_size,
                              hipStream_t stream) {
    const int*   idx = (const int*)d_in[0];
    // d_in[1] = attention_mask (bool) — unused: mask is frame(key) <= frame(query), computed analytically
    const float* ce  = (const float*)d_in[2];
    const float* se  = (const float*)d_in[3];
    const float* tp  = (const float*)d_in[4];
    const float* jp  = (const float*)d_in[5];
    const float* ipw = (const float*)d_in[6];
    const float* ipb = (const float*)d_in[7];
    const float* ow  = (const float*)d_in[8];
    const float* ob  = (const float*)d_in[9];
    const float* l1g = (const float*)d_in[10];
    const float* l1b = (const float*)d_in[11];
    const float* w1  = (const float*)d_in[12];
    const float* b1  = (const float*)d_in[13];
    const float* w2  = (const float*)d_in[14];
    const float* b2  = (const float*)d_in[15];
    const float* l2g = (const float*)d_in[16];
    const float* l2b = (const float*)d_in[17];

    float* x = (float*)d_out;                              // residual stream (fp32)
    // workspace layout (37.7 MB total):
    short* y_bf   = (short*)d_ws;                          // [4096][512]  bf16, 4 MiB
    short* qk_bf  = (short*)((char*)d_ws + (4u << 20));    // [4096][1024] bf16 (Q|K), 8 MiB
    short* vt_bf  = (short*)((char*)d_ws + (12u << 20));   // V^T [1024][2048] bf16, 4 MiB
    short* h_bf   = qk_bf;                                 // [4096][2048] bf16 overlays qk+vt (16 MiB)
    short* wb     = (short*)((char*)d_ws + (20u << 20));   // per-layer bf16 weights, 6.3 MiB
    short* wip = wb;                  // [1536][512]
    short* wob = wb + 786432;         // [512][512]
    short* w1b = wb + 1048576;        // [2048][512]
    short* w2b = wb + 2097152;        // [512][2048]
    short* opart = (short*)((char*)d_ws + (27u << 20));    // 2560 x [32][64] bf16, 10 MiB
    float* mlbuf = (float*)((char*)d_ws + (37u << 20));    // 2560 x [64] f32, 0.64 MiB

    embed_kernel<<<2048, 256, 0, stream>>>(idx, ce, se, tp, jp, x);

    for (int l = 0; l < NLAYER; ++l) {
        cast4_kernel<<<1536, 256, 0, stream>>>(
            ipw + (size_t)l * 786432, ow + (size_t)l * 262144,
            w1 + (size_t)l * 1048576, w2 + (size_t)l * 1048576, wb);
        ln_kernel<<<1024, 256, 0, stream>>>(x, y_bf, l1g + l * E, l1b + l * E);
        gemm_mfma_kernel<3><<<32 * 12, 256, 0, stream>>>(
            y_bf, wip, ipb + (size_t)l * 1536, nullptr, qk_bf, vt_bf, 1536, 512);
        attn_mfma_kernel<<<4096, 64, 0, stream>>>(qk_bf, vt_bf, opart, mlbuf);
        attn_combine_kernel<<<1024, 128, 0, stream>>>(opart, mlbuf, y_bf);
        gemm_mfma_kernel<1><<<32 * 4, 256, 0, stream>>>(
            y_bf, wob, ob + (size_t)l * E, x, x, nullptr, 512, 512);
        ln_kernel<<<1024, 256, 0, stream>>>(x, y_bf, l2g + l * E, l2b + l * E);
        gemm_mfma_kernel<2><<<32 * 16, 256, 0, stream>>>(
            y_bf, w1b, b1 + (size_t)l * DFF, nullptr, h_bf, nullptr, 2048, 512);
        gemm_mfma_kernel<1><<<32 * 4, 256, 0, stream>>>(
            h_bf, w2b, b2 + (size_t)l * E, x, x, nullptr, 512, 2048);
    }
}